// Round 11
// baseline (294.565 us; speedup 1.0000x reference)
//
#include <hip/hip_runtime.h>

#define N_NODES 50000
#define N_EDGES 800000
#define GEMM_BLKS ((N_NODES + 63) / 64)                  // 782
#define FILL_BLKS 4096
#define FRONT_BLKS (GEMM_BLKS + FILL_BLKS)
#define RANGE 6250                                       // dst-range per fill group
#define EDGES_PER_BLK 1564                               // ceil(800000/512)
#define MAXDEG 64
#define AGG1_BLKS (4 * (N_NODES / 8))                    // 4 groups x 6250 node-chunks
#define AGG2_BLKS (N_NODES / 4)

typedef __attribute__((ext_vector_type(8))) short bf16x8;
typedef __attribute__((ext_vector_type(4))) float f32x4;
typedef unsigned short u16;
typedef unsigned int u32;

__device__ __forceinline__ float lrelu(float x) { return x > 0.f ? x : 0.2f * x; }

__device__ __forceinline__ u16 f2bf(float f) {
    u32 u = __float_as_uint(f);
    return (u16)((u + 0x7FFFu + ((u >> 16) & 1u)) >> 16);
}
__device__ __forceinline__ float bflo(u32 w) { return __uint_as_float(w << 16); }
__device__ __forceinline__ float bfhi(u32 w) { return __uint_as_float(w & 0xFFFF0000u); }
__device__ __forceinline__ float elu(float x) { return x > 0.f ? x : __expf(x) - 1.f; }

// ================= Weight prep =================
__global__ __launch_bounds__(256) void k_prep(
    const float* __restrict__ W1, const float* __restrict__ as1v, const float* __restrict__ ad1v,
    const float* __restrict__ W2, const float* __restrict__ as2v, const float* __restrict__ ad2v,
    u16* __restrict__ Wt1, u16* __restrict__ Wt2)
{
    int gid = blockIdx.x * 256 + threadIdx.x;
    if (gid < 144 * 128) {
        int n = gid >> 7, k = gid & 127;
        float v = 0.f;
        if (n < 128) v = W1[k * 128 + n];
        else if (n < 136) {
            int h = n - 128;
            const float* att = (h < 4) ? as1v : ad1v;
            int hh = h & 3;
            float s = 0.f;
            for (int c = 0; c < 32; ++c) s += W1[k * 128 + hh * 32 + c] * att[hh * 32 + c];
            v = s;
        }
        Wt1[n * 128 + k] = f2bf(v);
    } else {
        int g2 = gid - 144 * 128;
        if (g2 < 80 * 128) {
            int n = g2 >> 7, k = g2 & 127;
            float v = 0.f;
            if (n < 64) v = W2[k * 64 + n];
            else if (n == 64) { float s = 0.f; for (int c = 0; c < 64; ++c) s += W2[k * 64 + c] * as2v[c]; v = s; }
            else if (n == 65) { float s = 0.f; for (int c = 0; c < 64; ++c) s += W2[k * 64 + c] * ad2v[c]; v = s; }
            Wt2[n * 128 + k] = f2bf(v);
        }
    }
}

// ====== Front: fused [gemm1 | bucketed CSR fill] (independent work, one launch) ======
// Blocks [0,782): layer-1 MFMA GEMM writing channel-group-major h1t + as/ad.
// Blocks [782,4878): dst-range-partitioned bucket fill of col16/deg.
__global__ __launch_bounds__(256) void k_front(
    const float* __restrict__ x, const u16* __restrict__ Wt1,
    u16* __restrict__ h1t, float* __restrict__ as_, float* __restrict__ ad_,
    const int* __restrict__ src, const int* __restrict__ dst,
    int* __restrict__ deg, u16* __restrict__ col16)
{
    __shared__ u16 xs[64][136];
    __shared__ u16 ws[144][136];
    const int t = threadIdx.x;
    if (blockIdx.x >= GEMM_BLKS) {
        // ---- fill part ----
        const int bb = blockIdx.x - GEMM_BLKS;
        const int g = bb & 7;
        const int b = bb >> 3;
        const int lo = g * RANGE;
        const int hi = min(lo + RANGE, N_NODES);
        const int e0 = b * EDGES_PER_BLK;
        const int e1 = min(e0 + EDGES_PER_BLK, N_EDGES);
        for (int e = e0 + t; e < e1; e += 256) {
            int v = dst[e];
            if (v >= lo && v < hi) {
                int pos = atomicAdd(&deg[v], 1);
                if (pos < MAXDEG) col16[v * MAXDEG + pos] = (u16)src[e];
            }
        }
        return;
    }
    // ---- gemm1 part ----
    const int n0 = blockIdx.x * 64;
    #pragma unroll
    for (int it = 0; it < 8; ++it) {
        int idx = it * 256 + t;
        int row = idx >> 5, c4 = (idx & 31) * 4;
        int n = n0 + row;
        float4 xv = make_float4(0.f, 0.f, 0.f, 0.f);
        if (n < N_NODES) xv = *(const float4*)&x[(size_t)n * 128 + c4];
        uint2 pk;
        pk.x = (u32)f2bf(xv.x) | ((u32)f2bf(xv.y) << 16);
        pk.y = (u32)f2bf(xv.z) | ((u32)f2bf(xv.w) << 16);
        *(uint2*)&xs[row][c4] = pk;
    }
    #pragma unroll
    for (int it = 0; it < 9; ++it) {
        int idx = it * 256 + t;
        int row = idx >> 4, c8 = (idx & 15) * 8;
        *(uint4*)&ws[row][c8] = *(const uint4*)&Wt1[row * 128 + c8];
    }
    __syncthreads();
    const int l = t & 63, w = t >> 6;
    const int lm = l & 15, quad = l >> 4;
    f32x4 acc[9];
    #pragma unroll
    for (int nt = 0; nt < 9; ++nt) acc[nt] = (f32x4){0.f, 0.f, 0.f, 0.f};
    const u16* arow = &xs[w * 16 + lm][0];
    #pragma unroll
    for (int kc = 0; kc < 4; ++kc) {
        int k0 = kc * 32 + quad * 8;
        bf16x8 a = *(const bf16x8*)&arow[k0];
        #pragma unroll
        for (int nt = 0; nt < 9; ++nt) {
            bf16x8 b = *(const bf16x8*)&ws[nt * 16 + lm][k0];
            acc[nt] = __builtin_amdgcn_mfma_f32_16x16x32_bf16(a, b, acc[nt], 0, 0, 0);
        }
    }
    #pragma unroll
    for (int r = 0; r < 4; ++r) {
        int n = n0 + w * 16 + quad * 4 + r;
        if (n >= N_NODES) continue;
        // channel-group-major: h1t[g][n][32], g = channel>>5 = nt>>1
        #pragma unroll
        for (int nt = 0; nt < 8; ++nt)
            h1t[(size_t)(nt >> 1) * N_NODES * 32 + (size_t)n * 32 + (nt & 1) * 16 + lm]
                = f2bf(acc[nt][r]);
        if (lm < 4)      as_[n * 4 + lm]     = acc[8][r];
        else if (lm < 8) ad_[n * 4 + lm - 4] = acc[8][r];
    }
}

// ====== Layer-1 aggregation v4: channel-group split (4 x 32ch = 1 head each) ======
// blockIdx&3 = group -> under round-robin dispatch a group lives on 2 XCDs whose L2
// holds that group's 3.2 MB h1t slice. Wave = 2 nodes x 2 edge-slots x 16 ch-lanes.
// No LDS, no barriers; col16/out1 nontemporal to protect the hot h1t slice in L2.
__global__ __launch_bounds__(256) void k_agg1(
    const int* __restrict__ deg, const u16* __restrict__ col16,
    const float* __restrict__ as_, const float* __restrict__ ad_,
    const u32* __restrict__ h1t, const float* __restrict__ b1,
    u32* __restrict__ out1u)
{
    const int g = blockIdx.x & 3;            // channel group == head
    const int nb = blockIdx.x >> 2;          // 0..6249
    const int t = threadIdx.x;
    const int w = t >> 6, l = t & 63;
    const int sub = l >> 5;                  // node within wave
    const int slot = (l >> 4) & 1;           // edge slot
    const int c = l & 15;                    // u32 (2 channels) within group
    const int v = nb * 8 + w * 2 + sub;
    const int dg = min(deg[v], MAXDEG);
    const float adh = ad_[v * 4 + g];
    const u32* hg = h1t + (size_t)g * N_NODES * 16;
    const u16* cr = col16 + v * MAXDEG;
    float a0 = 0.f, a1 = 0.f, s = 0.f;
    for (int i0 = slot; i0 < dg; i0 += 4) {
        int i1 = i0 + 2;
        bool m1 = i1 < dg;
        int u0 = __builtin_nontemporal_load(&cr[i0]);
        int u1 = __builtin_nontemporal_load(&cr[m1 ? i1 : i0]);
        float p0 = __expf(lrelu(as_[u0 * 4 + g] + adh));
        float p1 = m1 ? __expf(lrelu(as_[u1 * 4 + g] + adh)) : 0.f;
        u32 w0 = hg[u0 * 16 + c];
        u32 w1 = hg[u1 * 16 + c];
        a0 = fmaf(p0, bflo(w0), a0); a1 = fmaf(p0, bfhi(w0), a1);
        a0 = fmaf(p1, bflo(w1), a0); a1 = fmaf(p1, bfhi(w1), a1);
        s += p0 + p1;
    }
    a0 += __shfl_xor(a0, 16);
    a1 += __shfl_xor(a1, 16);
    s  += __shfl_xor(s, 16);
    if (slot == 0) {
        float inv = 1.f / (s + 1e-16f);
        int ch = g * 32 + 2 * c;
        float o0 = elu(a0 * inv + b1[ch]);
        float o1 = elu(a1 * inv + b1[ch + 1]);
        u32 pk = (u32)f2bf(o0) | ((u32)f2bf(o1) << 16);
        __builtin_nontemporal_store(pk, &out1u[(size_t)v * 64 + g * 16 + c]);
    }
}

// ================= Layer-2 MFMA GEMM (unchanged) =================
__global__ __launch_bounds__(256) void k_gemm2(
    const u16* __restrict__ xbf, const u16* __restrict__ Wt2,
    u16* __restrict__ hbf, float* __restrict__ as_, float* __restrict__ ad_)
{
    __shared__ u16 xs[64][136];
    __shared__ u16 ws[80][136];
    const int t = threadIdx.x;
    const int n0 = blockIdx.x * 64;
    #pragma unroll
    for (int it = 0; it < 4; ++it) {
        int idx = it * 256 + t;
        int row = idx >> 4, c8 = (idx & 15) * 8;
        int n = n0 + row;
        uint4 vv = make_uint4(0u, 0u, 0u, 0u);
        if (n < N_NODES) vv = *(const uint4*)&xbf[(size_t)n * 128 + c8];
        *(uint4*)&xs[row][c8] = vv;
    }
    #pragma unroll
    for (int it = 0; it < 5; ++it) {
        int idx = it * 256 + t;
        int row = idx >> 4, c8 = (idx & 15) * 8;
        *(uint4*)&ws[row][c8] = *(const uint4*)&Wt2[row * 128 + c8];
    }
    __syncthreads();
    const int l = t & 63, w = t >> 6;
    const int lm = l & 15, quad = l >> 4;
    f32x4 acc[5];
    #pragma unroll
    for (int nt = 0; nt < 5; ++nt) acc[nt] = (f32x4){0.f, 0.f, 0.f, 0.f};
    const u16* arow = &xs[w * 16 + lm][0];
    #pragma unroll
    for (int kc = 0; kc < 4; ++kc) {
        int k0 = kc * 32 + quad * 8;
        bf16x8 a = *(const bf16x8*)&arow[k0];
        #pragma unroll
        for (int nt = 0; nt < 5; ++nt) {
            bf16x8 b = *(const bf16x8*)&ws[nt * 16 + lm][k0];
            acc[nt] = __builtin_amdgcn_mfma_f32_16x16x32_bf16(a, b, acc[nt], 0, 0, 0);
        }
    }
    #pragma unroll
    for (int r = 0; r < 4; ++r) {
        int n = n0 + w * 16 + quad * 4 + r;
        if (n >= N_NODES) continue;
        #pragma unroll
        for (int nt = 0; nt < 4; ++nt)
            hbf[(size_t)n * 64 + nt * 16 + lm] = f2bf(acc[nt][r]);
        if (lm == 0)      as_[n] = acc[4][r];
        else if (lm == 1) ad_[n] = acc[4][r];
    }
}

// ========== Layer-2 aggregation: wave per node, no LDS/barriers (r10) + u16 col ==========
__global__ __launch_bounds__(256) void k_agg2(
    const int* __restrict__ deg, const u16* __restrict__ col16,
    const float* __restrict__ as_, const float* __restrict__ ad_,
    const u32* __restrict__ h2u, const float* __restrict__ b2,
    float* __restrict__ out)
{
    const int t = threadIdx.x;
    const int wv = t >> 6;
    const int l = t & 63;
    const int v = blockIdx.x * 4 + wv;
    const int c = l & 7;                // channel octet: channels 8c..8c+7
    const int slot = l >> 3;            // edge slot 0..7
    const int dg = min(deg[v], MAXDEG);
    const float adh = ad_[v];
    const u16* cr = col16 + v * MAXDEG;
    float a[8] = {0.f, 0.f, 0.f, 0.f, 0.f, 0.f, 0.f, 0.f};
    float s = 0.f;
    for (int i0 = slot; i0 < dg; i0 += 16) {
        int i1 = i0 + 8;
        bool m1 = i1 < dg;
        int u0 = __builtin_nontemporal_load(&cr[i0]);
        int u1 = __builtin_nontemporal_load(&cr[m1 ? i1 : i0]);
        float p0 = __expf(lrelu(as_[u0] + adh));
        float p1 = m1 ? __expf(lrelu(as_[u1] + adh)) : 0.f;
        uint4 w0 = *(const uint4*)(h2u + (u0 << 5) + (c << 2));
        uint4 w1 = *(const uint4*)(h2u + (u1 << 5) + (c << 2));
        a[0] = fmaf(p0, bflo(w0.x), a[0]); a[1] = fmaf(p0, bfhi(w0.x), a[1]);
        a[2] = fmaf(p0, bflo(w0.y), a[2]); a[3] = fmaf(p0, bfhi(w0.y), a[3]);
        a[4] = fmaf(p0, bflo(w0.z), a[4]); a[5] = fmaf(p0, bfhi(w0.z), a[5]);
        a[6] = fmaf(p0, bflo(w0.w), a[6]); a[7] = fmaf(p0, bfhi(w0.w), a[7]);
        a[0] = fmaf(p1, bflo(w1.x), a[0]); a[1] = fmaf(p1, bfhi(w1.x), a[1]);
        a[2] = fmaf(p1, bflo(w1.y), a[2]); a[3] = fmaf(p1, bfhi(w1.y), a[3]);
        a[4] = fmaf(p1, bflo(w1.z), a[4]); a[5] = fmaf(p1, bfhi(w1.z), a[5]);
        a[6] = fmaf(p1, bflo(w1.w), a[6]); a[7] = fmaf(p1, bfhi(w1.w), a[7]);
        s += p0 + p1;
    }
    #pragma unroll
    for (int k = 0; k < 8; ++k) {
        a[k] += __shfl_xor(a[k], 8);
        a[k] += __shfl_xor(a[k], 16);
        a[k] += __shfl_xor(a[k], 32);
    }
    s += __shfl_xor(s, 8);
    s += __shfl_xor(s, 16);
    s += __shfl_xor(s, 32);
    if (slot == 0) {
        float inv = 1.f / (s + 1e-16f);
        float4 b0 = *(const float4*)&b2[8 * c];
        float4 b4 = *(const float4*)&b2[8 * c + 4];
        float4 oa, ob;
        oa.x = a[0] * inv + b0.x;
        oa.y = a[1] * inv + b0.y;
        oa.z = a[2] * inv + b0.z;
        oa.w = a[3] * inv + b0.w;
        ob.x = a[4] * inv + b4.x;
        ob.y = a[5] * inv + b4.y;
        ob.z = a[6] * inv + b4.z;
        ob.w = a[7] * inv + b4.w;
        *(float4*)&out[(size_t)v * 64 + 8 * c]     = oa;
        *(float4*)&out[(size_t)v * 64 + 8 * c + 4] = ob;
    }
}

extern "C" void kernel_launch(void* const* d_in, const int* in_sizes, int n_in,
                              void* d_out, int out_size, void* d_ws, size_t ws_size,
                              hipStream_t stream)
{
    const float* x      = (const float*)d_in[0];
    const int*   ei     = (const int*)d_in[1];
    const float* W1     = (const float*)d_in[2];
    const float* att_s1 = (const float*)d_in[3];
    const float* att_d1 = (const float*)d_in[4];
    const float* b1     = (const float*)d_in[5];
    const float* W2     = (const float*)d_in[6];
    const float* att_s2 = (const float*)d_in[7];
    const float* att_d2 = (const float*)d_in[8];
    const float* b2     = (const float*)d_in[9];
    const int* src = ei;
    const int* dst = ei + N_EDGES;
    float* out = (float*)d_out;

    char* wsp = (char*)d_ws;
    u16* Wt1   = (u16*)wsp;  wsp += 144 * 128 * 2;
    u16* Wt2   = (u16*)wsp;  wsp += 80 * 128 * 2;
    u16* h1t   = (u16*)wsp;  wsp += (size_t)N_NODES * 128 * 2;       // 12.8 MB (group-major)
    u16* o1bf  = (u16*)wsp;  wsp += (size_t)N_NODES * 128 * 2;       // 12.8 MB
    u16* h2bf  = (u16*)wsp;  wsp += (size_t)N_NODES * 64 * 2;        // 6.4 MB
    float* as1 = (float*)wsp; wsp += (size_t)N_NODES * 4 * 4;
    float* ad1 = (float*)wsp; wsp += (size_t)N_NODES * 4 * 4;
    float* as2 = (float*)wsp; wsp += (size_t)N_NODES * 4;
    float* ad2 = (float*)wsp; wsp += (size_t)N_NODES * 4;
    int* deg   = (int*)wsp;   wsp += (size_t)N_NODES * 4;
    u16* col16 = (u16*)wsp;  wsp += (size_t)N_NODES * MAXDEG * 2;    // 6.4 MB

    k_prep<<<112, 256, 0, stream>>>(W1, att_s1, att_d1, W2, att_s2, att_d2, Wt1, Wt2);
    hipMemsetAsync(deg, 0, (size_t)N_NODES * 4, stream);
    k_front<<<FRONT_BLKS, 256, 0, stream>>>(x, Wt1, h1t, as1, ad1, src, dst, deg, col16);
    k_agg1<<<AGG1_BLKS, 256, 0, stream>>>(deg, col16, as1, ad1, (const u32*)h1t, b1, (u32*)o1bf);
    k_gemm2<<<GEMM_BLKS, 256, 0, stream>>>(o1bf, Wt2, h2bf, as2, ad2);
    k_agg2<<<AGG2_BLKS, 256, 0, stream>>>(deg, col16, as2, ad2, (const u32*)h2bf, b2, out);
}

// Round 12
// 286.749 us; speedup vs baseline: 1.0273x; 1.0273x over previous
//
#include <hip/hip_runtime.h>

#define N_NODES 50000
#define N_EDGES 800000
#define GEMM_BLKS ((N_NODES + 63) / 64)                  // 782
#define FILL_BLKS 4096
#define FRONT_BLKS (GEMM_BLKS + FILL_BLKS)
#define RANGE 6250                                       // dst-range per fill group
#define EDGES_PER_BLK 1564                               // ceil(800000/512)
#define MAXDEG 64
#define AGG1_BLKS (N_NODES)                              // (N/4 node-chunks) x 4 groups
#define AGG2_BLKS (N_NODES / 2)                          // (N/4 node-chunks) x 2 groups

typedef __attribute__((ext_vector_type(8))) short bf16x8;
typedef __attribute__((ext_vector_type(4))) float f32x4;
typedef unsigned short u16;
typedef unsigned int u32;

__device__ __forceinline__ float lrelu(float x) { return x > 0.f ? x : 0.2f * x; }

__device__ __forceinline__ u16 f2bf(float f) {
    u32 u = __float_as_uint(f);
    return (u16)((u + 0x7FFFu + ((u >> 16) & 1u)) >> 16);
}
__device__ __forceinline__ float bflo(u32 w) { return __uint_as_float(w << 16); }
__device__ __forceinline__ float bfhi(u32 w) { return __uint_as_float(w & 0xFFFF0000u); }
__device__ __forceinline__ float elu(float x) { return x > 0.f ? x : __expf(x) - 1.f; }

// ================= Weight prep =================
__global__ __launch_bounds__(256) void k_prep(
    const float* __restrict__ W1, const float* __restrict__ as1v, const float* __restrict__ ad1v,
    const float* __restrict__ W2, const float* __restrict__ as2v, const float* __restrict__ ad2v,
    u16* __restrict__ Wt1, u16* __restrict__ Wt2)
{
    int gid = blockIdx.x * 256 + threadIdx.x;
    if (gid < 144 * 128) {
        int n = gid >> 7, k = gid & 127;
        float v = 0.f;
        if (n < 128) v = W1[k * 128 + n];
        else if (n < 136) {
            int h = n - 128;
            const float* att = (h < 4) ? as1v : ad1v;
            int hh = h & 3;
            float s = 0.f;
            for (int c = 0; c < 32; ++c) s += W1[k * 128 + hh * 32 + c] * att[hh * 32 + c];
            v = s;
        }
        Wt1[n * 128 + k] = f2bf(v);
    } else {
        int g2 = gid - 144 * 128;
        if (g2 < 80 * 128) {
            int n = g2 >> 7, k = g2 & 127;
            float v = 0.f;
            if (n < 64) v = W2[k * 64 + n];
            else if (n == 64) { float s = 0.f; for (int c = 0; c < 64; ++c) s += W2[k * 64 + c] * as2v[c]; v = s; }
            else if (n == 65) { float s = 0.f; for (int c = 0; c < 64; ++c) s += W2[k * 64 + c] * ad2v[c]; v = s; }
            Wt2[n * 128 + k] = f2bf(v);
        }
    }
}

// ====== Front: fused [gemm1 | bucketed CSR fill] ======
__global__ __launch_bounds__(256) void k_front(
    const float* __restrict__ x, const u16* __restrict__ Wt1,
    u16* __restrict__ h1t, float* __restrict__ as_, float* __restrict__ ad_,
    const int* __restrict__ src, const int* __restrict__ dst,
    int* __restrict__ deg, u16* __restrict__ col16)
{
    __shared__ u16 xs[64][136];
    __shared__ u16 ws[144][136];
    const int t = threadIdx.x;
    if (blockIdx.x >= GEMM_BLKS) {
        const int bb = blockIdx.x - GEMM_BLKS;
        const int g = bb & 7;
        const int b = bb >> 3;
        const int lo = g * RANGE;
        const int hi = min(lo + RANGE, N_NODES);
        const int e0 = b * EDGES_PER_BLK;
        const int e1 = min(e0 + EDGES_PER_BLK, N_EDGES);
        for (int e = e0 + t; e < e1; e += 256) {
            int v = dst[e];
            if (v >= lo && v < hi) {
                int pos = atomicAdd(&deg[v], 1);
                if (pos < MAXDEG) col16[v * MAXDEG + pos] = (u16)src[e];
            }
        }
        return;
    }
    const int n0 = blockIdx.x * 64;
    #pragma unroll
    for (int it = 0; it < 8; ++it) {
        int idx = it * 256 + t;
        int row = idx >> 5, c4 = (idx & 31) * 4;
        int n = n0 + row;
        float4 xv = make_float4(0.f, 0.f, 0.f, 0.f);
        if (n < N_NODES) xv = *(const float4*)&x[(size_t)n * 128 + c4];
        uint2 pk;
        pk.x = (u32)f2bf(xv.x) | ((u32)f2bf(xv.y) << 16);
        pk.y = (u32)f2bf(xv.z) | ((u32)f2bf(xv.w) << 16);
        *(uint2*)&xs[row][c4] = pk;
    }
    #pragma unroll
    for (int it = 0; it < 9; ++it) {
        int idx = it * 256 + t;
        int row = idx >> 4, c8 = (idx & 15) * 8;
        *(uint4*)&ws[row][c8] = *(const uint4*)&Wt1[row * 128 + c8];
    }
    __syncthreads();
    const int l = t & 63, w = t >> 6;
    const int lm = l & 15, quad = l >> 4;
    f32x4 acc[9];
    #pragma unroll
    for (int nt = 0; nt < 9; ++nt) acc[nt] = (f32x4){0.f, 0.f, 0.f, 0.f};
    const u16* arow = &xs[w * 16 + lm][0];
    #pragma unroll
    for (int kc = 0; kc < 4; ++kc) {
        int k0 = kc * 32 + quad * 8;
        bf16x8 a = *(const bf16x8*)&arow[k0];
        #pragma unroll
        for (int nt = 0; nt < 9; ++nt) {
            bf16x8 b = *(const bf16x8*)&ws[nt * 16 + lm][k0];
            acc[nt] = __builtin_amdgcn_mfma_f32_16x16x32_bf16(a, b, acc[nt], 0, 0, 0);
        }
    }
    #pragma unroll
    for (int r = 0; r < 4; ++r) {
        int n = n0 + w * 16 + quad * 4 + r;
        if (n >= N_NODES) continue;
        // group-major: h1t[g][n][32ch], g = nt>>1
        #pragma unroll
        for (int nt = 0; nt < 8; ++nt)
            h1t[(size_t)(nt >> 1) * N_NODES * 32 + (size_t)n * 32 + (nt & 1) * 16 + lm]
                = f2bf(acc[nt][r]);
        if (lm < 4)      as_[n * 4 + lm]     = acc[8][r];
        else if (lm < 8) ad_[n * 4 + lm - 4] = acc[8][r];
    }
}

// ====== Layer-1 aggregation v5: group split + WIDE lanes ======
// blockIdx&3 = head-group (3.2 MB L2-resident slice); wave = 1 (node,group);
// lane = 16 edge-slots x 4 ch-lanes, each ch-lane gathers uint4 (8 ch) -- r10's
// load width with r11's traffic shape. Mean deg 16 == 16 slots. No LDS/barriers.
__global__ __launch_bounds__(256) void k_agg1(
    const int* __restrict__ deg, const u16* __restrict__ col16,
    const float* __restrict__ as_, const float* __restrict__ ad_,
    const u32* __restrict__ h1t, const float* __restrict__ b1,
    u32* __restrict__ out1u)
{
    const int g = blockIdx.x & 3;
    const int nb = blockIdx.x >> 2;
    const int t = threadIdx.x;
    const int w = t >> 6, l = t & 63;
    const int slot = l >> 2;             // 0..15
    const int c = l & 3;                 // uint4: channels 8c..8c+7 of group
    const int v = nb * 4 + w;
    const int dg = min(deg[v], MAXDEG);
    const float adh = ad_[v * 4 + g];
    const u32* hg = h1t + (size_t)g * N_NODES * 16;
    const u16* cr = col16 + v * MAXDEG;
    float a[8] = {0.f, 0.f, 0.f, 0.f, 0.f, 0.f, 0.f, 0.f};
    float s = 0.f;
    for (int i0 = slot; i0 < dg; i0 += 32) {
        int i1 = i0 + 16;
        bool m1 = i1 < dg;
        int u0 = cr[i0];
        int u1 = cr[m1 ? i1 : i0];
        float p0 = __expf(lrelu(as_[u0 * 4 + g] + adh));
        float p1 = m1 ? __expf(lrelu(as_[u1 * 4 + g] + adh)) : 0.f;
        uint4 w0 = *(const uint4*)(hg + u0 * 16 + c * 4);
        uint4 w1 = *(const uint4*)(hg + u1 * 16 + c * 4);
        a[0] = fmaf(p0, bflo(w0.x), a[0]); a[1] = fmaf(p0, bfhi(w0.x), a[1]);
        a[2] = fmaf(p0, bflo(w0.y), a[2]); a[3] = fmaf(p0, bfhi(w0.y), a[3]);
        a[4] = fmaf(p0, bflo(w0.z), a[4]); a[5] = fmaf(p0, bfhi(w0.z), a[5]);
        a[6] = fmaf(p0, bflo(w0.w), a[6]); a[7] = fmaf(p0, bfhi(w0.w), a[7]);
        a[0] = fmaf(p1, bflo(w1.x), a[0]); a[1] = fmaf(p1, bfhi(w1.x), a[1]);
        a[2] = fmaf(p1, bflo(w1.y), a[2]); a[3] = fmaf(p1, bfhi(w1.y), a[3]);
        a[4] = fmaf(p1, bflo(w1.z), a[4]); a[5] = fmaf(p1, bfhi(w1.z), a[5]);
        a[6] = fmaf(p1, bflo(w1.w), a[6]); a[7] = fmaf(p1, bfhi(w1.w), a[7]);
        s += p0 + p1;
    }
    // reduce over 16 slots (lanes sharing c): xor 4,8,16,32
    #pragma unroll
    for (int k = 0; k < 8; ++k) {
        a[k] += __shfl_xor(a[k], 4);
        a[k] += __shfl_xor(a[k], 8);
        a[k] += __shfl_xor(a[k], 16);
        a[k] += __shfl_xor(a[k], 32);
    }
    s += __shfl_xor(s, 4);
    s += __shfl_xor(s, 8);
    s += __shfl_xor(s, 16);
    s += __shfl_xor(s, 32);
    if (slot == 0) {
        float inv = 1.f / (s + 1e-16f);
        int ch = g * 32 + 8 * c;
        float4 b0 = *(const float4*)&b1[ch];
        float4 b4 = *(const float4*)&b1[ch + 4];
        float o0 = elu(a[0] * inv + b0.x);
        float o1 = elu(a[1] * inv + b0.y);
        float o2 = elu(a[2] * inv + b0.z);
        float o3 = elu(a[3] * inv + b0.w);
        float o4 = elu(a[4] * inv + b4.x);
        float o5 = elu(a[5] * inv + b4.y);
        float o6 = elu(a[6] * inv + b4.z);
        float o7 = elu(a[7] * inv + b4.w);
        uint4 pk;
        pk.x = (u32)f2bf(o0) | ((u32)f2bf(o1) << 16);
        pk.y = (u32)f2bf(o2) | ((u32)f2bf(o3) << 16);
        pk.z = (u32)f2bf(o4) | ((u32)f2bf(o5) << 16);
        pk.w = (u32)f2bf(o6) | ((u32)f2bf(o7) << 16);
        *(uint4*)(out1u + (size_t)v * 64 + g * 16 + 4 * c) = pk;
    }
}

// ================= Layer-2 MFMA GEMM: writes group-major h2t =================
__global__ __launch_bounds__(256) void k_gemm2(
    const u16* __restrict__ xbf, const u16* __restrict__ Wt2,
    u16* __restrict__ h2t, float* __restrict__ as_, float* __restrict__ ad_)
{
    __shared__ u16 xs[64][136];
    __shared__ u16 ws[80][136];
    const int t = threadIdx.x;
    const int n0 = blockIdx.x * 64;
    #pragma unroll
    for (int it = 0; it < 4; ++it) {
        int idx = it * 256 + t;
        int row = idx >> 4, c8 = (idx & 15) * 8;
        int n = n0 + row;
        uint4 vv = make_uint4(0u, 0u, 0u, 0u);
        if (n < N_NODES) vv = *(const uint4*)&xbf[(size_t)n * 128 + c8];
        *(uint4*)&xs[row][c8] = vv;
    }
    #pragma unroll
    for (int it = 0; it < 5; ++it) {
        int idx = it * 256 + t;
        int row = idx >> 4, c8 = (idx & 15) * 8;
        *(uint4*)&ws[row][c8] = *(const uint4*)&Wt2[row * 128 + c8];
    }
    __syncthreads();
    const int l = t & 63, w = t >> 6;
    const int lm = l & 15, quad = l >> 4;
    f32x4 acc[5];
    #pragma unroll
    for (int nt = 0; nt < 5; ++nt) acc[nt] = (f32x4){0.f, 0.f, 0.f, 0.f};
    const u16* arow = &xs[w * 16 + lm][0];
    #pragma unroll
    for (int kc = 0; kc < 4; ++kc) {
        int k0 = kc * 32 + quad * 8;
        bf16x8 a = *(const bf16x8*)&arow[k0];
        #pragma unroll
        for (int nt = 0; nt < 5; ++nt) {
            bf16x8 b = *(const bf16x8*)&ws[nt * 16 + lm][k0];
            acc[nt] = __builtin_amdgcn_mfma_f32_16x16x32_bf16(a, b, acc[nt], 0, 0, 0);
        }
    }
    #pragma unroll
    for (int r = 0; r < 4; ++r) {
        int n = n0 + w * 16 + quad * 4 + r;
        if (n >= N_NODES) continue;
        // group-major: h2t[g][n][32ch], g = nt>>1
        #pragma unroll
        for (int nt = 0; nt < 4; ++nt)
            h2t[(size_t)(nt >> 1) * N_NODES * 32 + (size_t)n * 32 + (nt & 1) * 16 + lm]
                = f2bf(acc[nt][r]);
        if (lm == 0)      as_[n] = acc[4][r];
        else if (lm == 1) ad_[n] = acc[4][r];
    }
}

// ====== Layer-2 aggregation v5: 2-group split + wide lanes ======
__global__ __launch_bounds__(256) void k_agg2(
    const int* __restrict__ deg, const u16* __restrict__ col16,
    const float* __restrict__ as_, const float* __restrict__ ad_,
    const u32* __restrict__ h2t, const float* __restrict__ b2,
    float* __restrict__ out)
{
    const int g = blockIdx.x & 1;
    const int nb = blockIdx.x >> 1;
    const int t = threadIdx.x;
    const int w = t >> 6, l = t & 63;
    const int slot = l >> 2;             // 0..15
    const int c = l & 3;                 // uint4: channels 8c..8c+7 of group
    const int v = nb * 4 + w;
    const int dg = min(deg[v], MAXDEG);
    const float adh = ad_[v];
    const u32* hg = h2t + (size_t)g * N_NODES * 16;
    const u16* cr = col16 + v * MAXDEG;
    float a[8] = {0.f, 0.f, 0.f, 0.f, 0.f, 0.f, 0.f, 0.f};
    float s = 0.f;
    for (int i0 = slot; i0 < dg; i0 += 32) {
        int i1 = i0 + 16;
        bool m1 = i1 < dg;
        int u0 = cr[i0];
        int u1 = cr[m1 ? i1 : i0];
        float p0 = __expf(lrelu(as_[u0] + adh));
        float p1 = m1 ? __expf(lrelu(as_[u1] + adh)) : 0.f;
        uint4 w0 = *(const uint4*)(hg + u0 * 16 + c * 4);
        uint4 w1 = *(const uint4*)(hg + u1 * 16 + c * 4);
        a[0] = fmaf(p0, bflo(w0.x), a[0]); a[1] = fmaf(p0, bfhi(w0.x), a[1]);
        a[2] = fmaf(p0, bflo(w0.y), a[2]); a[3] = fmaf(p0, bfhi(w0.y), a[3]);
        a[4] = fmaf(p0, bflo(w0.z), a[4]); a[5] = fmaf(p0, bfhi(w0.z), a[5]);
        a[6] = fmaf(p0, bflo(w0.w), a[6]); a[7] = fmaf(p0, bfhi(w0.w), a[7]);
        a[0] = fmaf(p1, bflo(w1.x), a[0]); a[1] = fmaf(p1, bfhi(w1.x), a[1]);
        a[2] = fmaf(p1, bflo(w1.y), a[2]); a[3] = fmaf(p1, bfhi(w1.y), a[3]);
        a[4] = fmaf(p1, bflo(w1.z), a[4]); a[5] = fmaf(p1, bfhi(w1.z), a[5]);
        a[6] = fmaf(p1, bflo(w1.w), a[6]); a[7] = fmaf(p1, bfhi(w1.w), a[7]);
        s += p0 + p1;
    }
    #pragma unroll
    for (int k = 0; k < 8; ++k) {
        a[k] += __shfl_xor(a[k], 4);
        a[k] += __shfl_xor(a[k], 8);
        a[k] += __shfl_xor(a[k], 16);
        a[k] += __shfl_xor(a[k], 32);
    }
    s += __shfl_xor(s, 4);
    s += __shfl_xor(s, 8);
    s += __shfl_xor(s, 16);
    s += __shfl_xor(s, 32);
    if (slot == 0) {
        float inv = 1.f / (s + 1e-16f);
        int ch = g * 32 + 8 * c;
        float4 b0 = *(const float4*)&b2[ch];
        float4 b4 = *(const float4*)&b2[ch + 4];
        float4 oa, ob;
        oa.x = a[0] * inv + b0.x;
        oa.y = a[1] * inv + b0.y;
        oa.z = a[2] * inv + b0.z;
        oa.w = a[3] * inv + b0.w;
        ob.x = a[4] * inv + b4.x;
        ob.y = a[5] * inv + b4.y;
        ob.z = a[6] * inv + b4.z;
        ob.w = a[7] * inv + b4.w;
        *(float4*)&out[(size_t)v * 64 + ch]     = oa;
        *(float4*)&out[(size_t)v * 64 + ch + 4] = ob;
    }
}

extern "C" void kernel_launch(void* const* d_in, const int* in_sizes, int n_in,
                              void* d_out, int out_size, void* d_ws, size_t ws_size,
                              hipStream_t stream)
{
    const float* x      = (const float*)d_in[0];
    const int*   ei     = (const int*)d_in[1];
    const float* W1     = (const float*)d_in[2];
    const float* att_s1 = (const float*)d_in[3];
    const float* att_d1 = (const float*)d_in[4];
    const float* b1     = (const float*)d_in[5];
    const float* W2     = (const float*)d_in[6];
    const float* att_s2 = (const float*)d_in[7];
    const float* att_d2 = (const float*)d_in[8];
    const float* b2     = (const float*)d_in[9];
    const int* src = ei;
    const int* dst = ei + N_EDGES;
    float* out = (float*)d_out;

    char* wsp = (char*)d_ws;
    u16* Wt1   = (u16*)wsp;  wsp += 144 * 128 * 2;
    u16* Wt2   = (u16*)wsp;  wsp += 80 * 128 * 2;
    u16* h1t   = (u16*)wsp;  wsp += (size_t)N_NODES * 128 * 2;       // 12.8 MB (group-major)
    u16* o1bf  = (u16*)wsp;  wsp += (size_t)N_NODES * 128 * 2;       // 12.8 MB (node-major)
    u16* h2t   = (u16*)wsp;  wsp += (size_t)N_NODES * 64 * 2;        // 6.4 MB (group-major)
    float* as1 = (float*)wsp; wsp += (size_t)N_NODES * 4 * 4;
    float* ad1 = (float*)wsp; wsp += (size_t)N_NODES * 4 * 4;
    float* as2 = (float*)wsp; wsp += (size_t)N_NODES * 4;
    float* ad2 = (float*)wsp; wsp += (size_t)N_NODES * 4;
    int* deg   = (int*)wsp;   wsp += (size_t)N_NODES * 4;
    u16* col16 = (u16*)wsp;  wsp += (size_t)N_NODES * MAXDEG * 2;    // 6.4 MB

    k_prep<<<112, 256, 0, stream>>>(W1, att_s1, att_d1, W2, att_s2, att_d2, Wt1, Wt2);
    hipMemsetAsync(deg, 0, (size_t)N_NODES * 4, stream);
    k_front<<<FRONT_BLKS, 256, 0, stream>>>(x, Wt1, h1t, as1, ad1, src, dst, deg, col16);
    k_agg1<<<AGG1_BLKS, 256, 0, stream>>>(deg, col16, as1, ad1, (const u32*)h1t, b1, (u32*)o1bf);
    k_gemm2<<<GEMM_BLKS, 256, 0, stream>>>(o1bf, Wt2, h2t, as2, ad2);
    k_agg2<<<AGG2_BLKS, 256, 0, stream>>>(deg, col16, as2, ad2, (const u32*)h2t, b2, out);
}

// Round 13
// 205.535 us; speedup vs baseline: 1.4332x; 1.3951x over previous
//
#include <hip/hip_runtime.h>

#define N_NODES 50000
#define N_EDGES 800000
#define GEMM_BLKS ((N_NODES + 63) / 64)                  // 782
#define FILL_BLKS 4096                                   // 512 blocks per dst-range group
#define RANGE 6250                                       // dst-range per fill group
#define EDGES_PER_BLK 1564                               // ceil(800000/512)
#define MAXDEG 64
#define AGG_BLKS (N_NODES / 4)                           // 4 nodes (waves) per block

typedef __attribute__((ext_vector_type(8))) short bf16x8;
typedef __attribute__((ext_vector_type(4))) float f32x4;
typedef unsigned short u16;
typedef unsigned int u32;

__device__ __forceinline__ float lrelu(float x) { return x > 0.f ? x : 0.2f * x; }

__device__ __forceinline__ u16 f2bf(float f) {
    u32 u = __float_as_uint(f);
    return (u16)((u + 0x7FFFu + ((u >> 16) & 1u)) >> 16);
}
__device__ __forceinline__ float bflo(u32 w) { return __uint_as_float(w << 16); }
__device__ __forceinline__ float bfhi(u32 w) { return __uint_as_float(w & 0xFFFF0000u); }
__device__ __forceinline__ float elu(float x) { return x > 0.f ? x : __expf(x) - 1.f; }

// ================= Weight prep + deg zeroing (one launch) =================
__global__ __launch_bounds__(256) void k_prep(
    const float* __restrict__ W1, const float* __restrict__ as1v, const float* __restrict__ ad1v,
    const float* __restrict__ W2, const float* __restrict__ as2v, const float* __restrict__ ad2v,
    u16* __restrict__ Wt1, u16* __restrict__ Wt2, int* __restrict__ deg)
{
    int gid = blockIdx.x * 256 + threadIdx.x;
    for (int i = gid; i < N_NODES; i += 112 * 256) deg[i] = 0;   // replaces hipMemsetAsync
    if (gid < 144 * 128) {
        int n = gid >> 7, k = gid & 127;
        float v = 0.f;
        if (n < 128) v = W1[k * 128 + n];
        else if (n < 136) {
            int h = n - 128;
            const float* att = (h < 4) ? as1v : ad1v;
            int hh = h & 3;
            float s = 0.f;
            for (int c = 0; c < 32; ++c) s += W1[k * 128 + hh * 32 + c] * att[hh * 32 + c];
            v = s;
        }
        Wt1[n * 128 + k] = f2bf(v);
    } else {
        int g2 = gid - 144 * 128;
        if (g2 < 80 * 128) {
            int n = g2 >> 7, k = g2 & 127;
            float v = 0.f;
            if (n < 64) v = W2[k * 64 + n];
            else if (n == 64) { float s = 0.f; for (int c = 0; c < 64; ++c) s += W2[k * 64 + c] * as2v[c]; v = s; }
            else if (n == 65) { float s = 0.f; for (int c = 0; c < 64; ++c) s += W2[k * 64 + c] * ad2v[c]; v = s; }
            Wt2[n * 128 + k] = f2bf(v);
        }
    }
}

// ================= Bucketed CSR fill (u16 col) =================
__global__ __launch_bounds__(256) void k_fill(
    const int* __restrict__ src, const int* __restrict__ dst,
    int* __restrict__ deg, u16* __restrict__ col16)
{
    const int g = blockIdx.x & 7;
    const int b = blockIdx.x >> 3;
    const int lo = g * RANGE;
    const int hi = min(lo + RANGE, N_NODES);
    const int e0 = b * EDGES_PER_BLK;
    const int e1 = min(e0 + EDGES_PER_BLK, N_EDGES);
    for (int e = e0 + threadIdx.x; e < e1; e += 256) {
        int v = dst[e];
        if (v >= lo && v < hi) {
            int pos = atomicAdd(&deg[v], 1);
            if (pos < MAXDEG) col16[v * MAXDEG + pos] = (u16)src[e];
        }
    }
}

// ================= Layer-1 MFMA GEMM: node-major h1 (r10) =================
__global__ __launch_bounds__(256) void k_gemm1(
    const float* __restrict__ x, const u16* __restrict__ Wt1,
    u16* __restrict__ hbf, float* __restrict__ as_, float* __restrict__ ad_)
{
    __shared__ u16 xs[64][136];
    __shared__ u16 ws[144][136];
    const int t = threadIdx.x;
    const int n0 = blockIdx.x * 64;
    #pragma unroll
    for (int it = 0; it < 8; ++it) {
        int idx = it * 256 + t;
        int row = idx >> 5, c4 = (idx & 31) * 4;
        int n = n0 + row;
        float4 xv = make_float4(0.f, 0.f, 0.f, 0.f);
        if (n < N_NODES) xv = *(const float4*)&x[(size_t)n * 128 + c4];
        uint2 pk;
        pk.x = (u32)f2bf(xv.x) | ((u32)f2bf(xv.y) << 16);
        pk.y = (u32)f2bf(xv.z) | ((u32)f2bf(xv.w) << 16);
        *(uint2*)&xs[row][c4] = pk;
    }
    #pragma unroll
    for (int it = 0; it < 9; ++it) {
        int idx = it * 256 + t;
        int row = idx >> 4, c8 = (idx & 15) * 8;
        *(uint4*)&ws[row][c8] = *(const uint4*)&Wt1[row * 128 + c8];
    }
    __syncthreads();
    const int l = t & 63, w = t >> 6;
    const int lm = l & 15, quad = l >> 4;
    f32x4 acc[9];
    #pragma unroll
    for (int nt = 0; nt < 9; ++nt) acc[nt] = (f32x4){0.f, 0.f, 0.f, 0.f};
    const u16* arow = &xs[w * 16 + lm][0];
    #pragma unroll
    for (int kc = 0; kc < 4; ++kc) {
        int k0 = kc * 32 + quad * 8;
        bf16x8 a = *(const bf16x8*)&arow[k0];
        #pragma unroll
        for (int nt = 0; nt < 9; ++nt) {
            bf16x8 b = *(const bf16x8*)&ws[nt * 16 + lm][k0];
            acc[nt] = __builtin_amdgcn_mfma_f32_16x16x32_bf16(a, b, acc[nt], 0, 0, 0);
        }
    }
    #pragma unroll
    for (int r = 0; r < 4; ++r) {
        int n = n0 + w * 16 + quad * 4 + r;
        if (n >= N_NODES) continue;
        #pragma unroll
        for (int nt = 0; nt < 8; ++nt)
            hbf[(size_t)n * 128 + nt * 16 + lm] = f2bf(acc[nt][r]);
        if (lm < 4)      as_[n * 4 + lm]     = acc[8][r];
        else if (lm < 8) ad_[n * 4 + lm - 4] = acc[8][r];
    }
}

// ========== Layer-1 aggregation (r10 v3): wave/node, no LDS/barriers, u16 col ==========
__global__ __launch_bounds__(256) void k_agg1(
    const int* __restrict__ deg, const u16* __restrict__ col16,
    const float* __restrict__ as_, const float* __restrict__ ad_,
    const u32* __restrict__ h1u, const float* __restrict__ b1,
    u32* __restrict__ out1u)
{
    const int t = threadIdx.x;
    const int wv = t >> 6;              // wave = node unit
    const int l = t & 63;
    const int v = blockIdx.x * 4 + wv;
    const int c = l & 15;               // channel octet: channels 8c..8c+7
    const int slot = l >> 4;            // edge slot 0..3
    const int hh = c >> 2;              // head of this octet
    const int dg = min(deg[v], MAXDEG);
    const float adh = ad_[v * 4 + hh];
    const u16* cr = col16 + v * MAXDEG;
    float a[8] = {0.f, 0.f, 0.f, 0.f, 0.f, 0.f, 0.f, 0.f};
    float s = 0.f;
    for (int i0 = slot; i0 < dg; i0 += 8) {
        int i1 = i0 + 4;
        bool m1 = i1 < dg;
        int u0 = cr[i0];
        int u1 = cr[m1 ? i1 : i0];
        float p0 = __expf(lrelu(as_[u0 * 4 + hh] + adh));
        float p1 = m1 ? __expf(lrelu(as_[u1 * 4 + hh] + adh)) : 0.f;
        uint4 w0 = *(const uint4*)(h1u + (u0 << 6) + (c << 2));
        uint4 w1 = *(const uint4*)(h1u + (u1 << 6) + (c << 2));
        a[0] = fmaf(p0, bflo(w0.x), a[0]); a[1] = fmaf(p0, bfhi(w0.x), a[1]);
        a[2] = fmaf(p0, bflo(w0.y), a[2]); a[3] = fmaf(p0, bfhi(w0.y), a[3]);
        a[4] = fmaf(p0, bflo(w0.z), a[4]); a[5] = fmaf(p0, bfhi(w0.z), a[5]);
        a[6] = fmaf(p0, bflo(w0.w), a[6]); a[7] = fmaf(p0, bfhi(w0.w), a[7]);
        a[0] = fmaf(p1, bflo(w1.x), a[0]); a[1] = fmaf(p1, bfhi(w1.x), a[1]);
        a[2] = fmaf(p1, bflo(w1.y), a[2]); a[3] = fmaf(p1, bfhi(w1.y), a[3]);
        a[4] = fmaf(p1, bflo(w1.z), a[4]); a[5] = fmaf(p1, bfhi(w1.z), a[5]);
        a[6] = fmaf(p1, bflo(w1.w), a[6]); a[7] = fmaf(p1, bfhi(w1.w), a[7]);
        s += p0 + p1;
    }
    #pragma unroll
    for (int k = 0; k < 8; ++k) {
        a[k] += __shfl_xor(a[k], 16);
        a[k] += __shfl_xor(a[k], 32);
    }
    s += __shfl_xor(s, 16);
    s += __shfl_xor(s, 32);
    if (slot == 0) {
        float inv = 1.f / (s + 1e-16f);
        float4 b0 = *(const float4*)&b1[8 * c];
        float4 b4 = *(const float4*)&b1[8 * c + 4];
        float o0 = elu(a[0] * inv + b0.x);
        float o1 = elu(a[1] * inv + b0.y);
        float o2 = elu(a[2] * inv + b0.z);
        float o3 = elu(a[3] * inv + b0.w);
        float o4 = elu(a[4] * inv + b4.x);
        float o5 = elu(a[5] * inv + b4.y);
        float o6 = elu(a[6] * inv + b4.z);
        float o7 = elu(a[7] * inv + b4.w);
        uint4 pk;
        pk.x = (u32)f2bf(o0) | ((u32)f2bf(o1) << 16);
        pk.y = (u32)f2bf(o2) | ((u32)f2bf(o3) << 16);
        pk.z = (u32)f2bf(o4) | ((u32)f2bf(o5) << 16);
        pk.w = (u32)f2bf(o6) | ((u32)f2bf(o7) << 16);
        *(uint4*)(out1u + v * 64 + 4 * c) = pk;
    }
}

// ================= Layer-2 MFMA GEMM: node-major h2 (r10) =================
__global__ __launch_bounds__(256) void k_gemm2(
    const u16* __restrict__ xbf, const u16* __restrict__ Wt2,
    u16* __restrict__ hbf, float* __restrict__ as_, float* __restrict__ ad_)
{
    __shared__ u16 xs[64][136];
    __shared__ u16 ws[80][136];
    const int t = threadIdx.x;
    const int n0 = blockIdx.x * 64;
    #pragma unroll
    for (int it = 0; it < 4; ++it) {
        int idx = it * 256 + t;
        int row = idx >> 4, c8 = (idx & 15) * 8;
        int n = n0 + row;
        uint4 vv = make_uint4(0u, 0u, 0u, 0u);
        if (n < N_NODES) vv = *(const uint4*)&xbf[(size_t)n * 128 + c8];
        *(uint4*)&xs[row][c8] = vv;
    }
    #pragma unroll
    for (int it = 0; it < 5; ++it) {
        int idx = it * 256 + t;
        int row = idx >> 4, c8 = (idx & 15) * 8;
        *(uint4*)&ws[row][c8] = *(const uint4*)&Wt2[row * 128 + c8];
    }
    __syncthreads();
    const int l = t & 63, w = t >> 6;
    const int lm = l & 15, quad = l >> 4;
    f32x4 acc[5];
    #pragma unroll
    for (int nt = 0; nt < 5; ++nt) acc[nt] = (f32x4){0.f, 0.f, 0.f, 0.f};
    const u16* arow = &xs[w * 16 + lm][0];
    #pragma unroll
    for (int kc = 0; kc < 4; ++kc) {
        int k0 = kc * 32 + quad * 8;
        bf16x8 a = *(const bf16x8*)&arow[k0];
        #pragma unroll
        for (int nt = 0; nt < 5; ++nt) {
            bf16x8 b = *(const bf16x8*)&ws[nt * 16 + lm][k0];
            acc[nt] = __builtin_amdgcn_mfma_f32_16x16x32_bf16(a, b, acc[nt], 0, 0, 0);
        }
    }
    #pragma unroll
    for (int r = 0; r < 4; ++r) {
        int n = n0 + w * 16 + quad * 4 + r;
        if (n >= N_NODES) continue;
        #pragma unroll
        for (int nt = 0; nt < 4; ++nt)
            hbf[(size_t)n * 64 + nt * 16 + lm] = f2bf(acc[nt][r]);
        if (lm == 0)      as_[n] = acc[4][r];
        else if (lm == 1) ad_[n] = acc[4][r];
    }
}

// ========== Layer-2 aggregation (r10 v3): wave/node, no LDS/barriers, u16 col ==========
__global__ __launch_bounds__(256) void k_agg2(
    const int* __restrict__ deg, const u16* __restrict__ col16,
    const float* __restrict__ as_, const float* __restrict__ ad_,
    const u32* __restrict__ h2u, const float* __restrict__ b2,
    float* __restrict__ out)
{
    const int t = threadIdx.x;
    const int wv = t >> 6;
    const int l = t & 63;
    const int v = blockIdx.x * 4 + wv;
    const int c = l & 7;                // channel octet: channels 8c..8c+7
    const int slot = l >> 3;            // edge slot 0..7
    const int dg = min(deg[v], MAXDEG);
    const float adh = ad_[v];
    const u16* cr = col16 + v * MAXDEG;
    float a[8] = {0.f, 0.f, 0.f, 0.f, 0.f, 0.f, 0.f, 0.f};
    float s = 0.f;
    for (int i0 = slot; i0 < dg; i0 += 16) {
        int i1 = i0 + 8;
        bool m1 = i1 < dg;
        int u0 = cr[i0];
        int u1 = cr[m1 ? i1 : i0];
        float p0 = __expf(lrelu(as_[u0] + adh));
        float p1 = m1 ? __expf(lrelu(as_[u1] + adh)) : 0.f;
        uint4 w0 = *(const uint4*)(h2u + (u0 << 5) + (c << 2));
        uint4 w1 = *(const uint4*)(h2u + (u1 << 5) + (c << 2));
        a[0] = fmaf(p0, bflo(w0.x), a[0]); a[1] = fmaf(p0, bfhi(w0.x), a[1]);
        a[2] = fmaf(p0, bflo(w0.y), a[2]); a[3] = fmaf(p0, bfhi(w0.y), a[3]);
        a[4] = fmaf(p0, bflo(w0.z), a[4]); a[5] = fmaf(p0, bfhi(w0.z), a[5]);
        a[6] = fmaf(p0, bflo(w0.w), a[6]); a[7] = fmaf(p0, bfhi(w0.w), a[7]);
        a[0] = fmaf(p1, bflo(w1.x), a[0]); a[1] = fmaf(p1, bfhi(w1.x), a[1]);
        a[2] = fmaf(p1, bflo(w1.y), a[2]); a[3] = fmaf(p1, bfhi(w1.y), a[3]);
        a[4] = fmaf(p1, bflo(w1.z), a[4]); a[5] = fmaf(p1, bfhi(w1.z), a[5]);
        a[6] = fmaf(p1, bflo(w1.w), a[6]); a[7] = fmaf(p1, bfhi(w1.w), a[7]);
        s += p0 + p1;
    }
    #pragma unroll
    for (int k = 0; k < 8; ++k) {
        a[k] += __shfl_xor(a[k], 8);
        a[k] += __shfl_xor(a[k], 16);
        a[k] += __shfl_xor(a[k], 32);
    }
    s += __shfl_xor(s, 8);
    s += __shfl_xor(s, 16);
    s += __shfl_xor(s, 32);
    if (slot == 0) {
        float inv = 1.f / (s + 1e-16f);
        float4 b0 = *(const float4*)&b2[8 * c];
        float4 b4 = *(const float4*)&b2[8 * c + 4];
        float4 oa, ob;
        oa.x = a[0] * inv + b0.x;
        oa.y = a[1] * inv + b0.y;
        oa.z = a[2] * inv + b0.z;
        oa.w = a[3] * inv + b0.w;
        ob.x = a[4] * inv + b4.x;
        ob.y = a[5] * inv + b4.y;
        ob.z = a[6] * inv + b4.z;
        ob.w = a[7] * inv + b4.w;
        *(float4*)&out[(size_t)v * 64 + 8 * c]     = oa;
        *(float4*)&out[(size_t)v * 64 + 8 * c + 4] = ob;
    }
}

extern "C" void kernel_launch(void* const* d_in, const int* in_sizes, int n_in,
                              void* d_out, int out_size, void* d_ws, size_t ws_size,
                              hipStream_t stream)
{
    const float* x      = (const float*)d_in[0];
    const int*   ei     = (const int*)d_in[1];
    const float* W1     = (const float*)d_in[2];
    const float* att_s1 = (const float*)d_in[3];
    const float* att_d1 = (const float*)d_in[4];
    const float* b1     = (const float*)d_in[5];
    const float* W2     = (const float*)d_in[6];
    const float* att_s2 = (const float*)d_in[7];
    const float* att_d2 = (const float*)d_in[8];
    const float* b2     = (const float*)d_in[9];
    const int* src = ei;
    const int* dst = ei + N_EDGES;
    float* out = (float*)d_out;

    char* wsp = (char*)d_ws;
    u16* Wt1   = (u16*)wsp;  wsp += 144 * 128 * 2;
    u16* Wt2   = (u16*)wsp;  wsp += 80 * 128 * 2;
    u16* h1bf  = (u16*)wsp;  wsp += (size_t)N_NODES * 128 * 2;       // 12.8 MB
    u16* o1bf  = (u16*)wsp;  wsp += (size_t)N_NODES * 128 * 2;       // 12.8 MB
    u16* h2bf  = (u16*)wsp;  wsp += (size_t)N_NODES * 64 * 2;        // 6.4 MB
    float* as1 = (float*)wsp; wsp += (size_t)N_NODES * 4 * 4;
    float* ad1 = (float*)wsp; wsp += (size_t)N_NODES * 4 * 4;
    float* as2 = (float*)wsp; wsp += (size_t)N_NODES * 4;
    float* ad2 = (float*)wsp; wsp += (size_t)N_NODES * 4;
    int* deg   = (int*)wsp;   wsp += (size_t)N_NODES * 4;
    u16* col16 = (u16*)wsp;  wsp += (size_t)N_NODES * MAXDEG * 2;    // 6.4 MB

    k_prep<<<112, 256, 0, stream>>>(W1, att_s1, att_d1, W2, att_s2, att_d2, Wt1, Wt2, deg);
    k_fill<<<FILL_BLKS, 256, 0, stream>>>(src, dst, deg, col16);

    k_gemm1<<<GEMM_BLKS, 256, 0, stream>>>(x, Wt1, h1bf, as1, ad1);
    k_agg1<<<AGG_BLKS, 256, 0, stream>>>(deg, col16, as1, ad1, (const u32*)h1bf, b1, (u32*)o1bf);

    k_gemm2<<<GEMM_BLKS, 256, 0, stream>>>(o1bf, Wt2, h2bf, as2, ad2);
    k_agg2<<<AGG_BLKS, 256, 0, stream>>>(deg, col16, as2, ad2, (const u32*)h2bf, b2, out);
}